// Round 14
// baseline (12944.196 us; speedup 1.0000x reference)
//
#include <hip/hip_runtime.h>

typedef unsigned short u16;
typedef unsigned int u32;
typedef unsigned long long u64;
typedef __attribute__((ext_vector_type(4))) float f32x4;
typedef __attribute__((ext_vector_type(8))) short bf16x8;
typedef __attribute__((ext_vector_type(4))) u16 u16x4;
typedef __attribute__((ext_vector_type(8))) u16 u16x8;
typedef __attribute__((ext_vector_type(4))) u32 u32x4;

#define AGENT_SCOPE __HIP_MEMORY_SCOPE_AGENT

__device__ __forceinline__ int loadai(const int* p) {
  return __hip_atomic_load((int*)p, __ATOMIC_RELAXED, AGENT_SCOPE);
}
__device__ __forceinline__ void sta32(u32* p, u32 v) {
  __hip_atomic_store(p, v, __ATOMIC_RELAXED, AGENT_SCOPE);
}

__device__ __forceinline__ u16 f2bf(float f) {
  u32 u = __builtin_bit_cast(u32, f);
  u = (u + 0x7FFFu + ((u >> 16) & 1u)) >> 16;
  return (u16)u;
}
__device__ __forceinline__ float b2f(u16 h) {
  return __builtin_bit_cast(float, ((u32)h) << 16);
}
__device__ __forceinline__ float sigf(float x) { return 1.0f / (1.0f + __expf(-x)); }
__device__ __forceinline__ float tanh_(float x) { return 2.0f / (1.0f + __expf(-2.0f * x)) - 1.0f; }

// ---------------------------------------------------------------------------
// fp32 -> bf16 elementwise (vectorized)
// ---------------------------------------------------------------------------
__global__ __launch_bounds__(256) void cvt_bf16_vec(
    const float* __restrict__ in, u16* __restrict__ out, int n4)
{
  int i = blockIdx.x * blockDim.x + threadIdx.x;
  const int stride = gridDim.x * blockDim.x;
  for (; i < n4; i += stride) {
    f32x4 v = ((const f32x4*)in)[i];
    u16x4 o;
    #pragma unroll
    for (int e = 0; e < 4; ++e) o[e] = f2bf(v[e]);
    ((u16x4*)out)[i] = o;
  }
}

// ---------------------------------------------------------------------------
// fp32 (R x C) -> bf16 transposed (C x R)
// ---------------------------------------------------------------------------
__global__ __launch_bounds__(256) void transpose_f32_bf16(
    const float* __restrict__ in, u16* __restrict__ out, int R, int C)
{
  __shared__ float t[32][33];
  const int tx = threadIdx.x & 31, ty = threadIdx.x >> 5; // ty in [0,8)
  const int bx = blockIdx.x * 32, by = blockIdx.y * 32;
  #pragma unroll
  for (int i = 0; i < 4; ++i)
    t[ty + i * 8][tx] = in[(long)(by + ty + i * 8) * C + bx + tx];
  __syncthreads();
  #pragma unroll
  for (int i = 0; i < 4; ++i)
    out[(long)(bx + ty + i * 8) * R + by + tx] = f2bf(t[tx][ty + i * 8]);
}

// ---------------------------------------------------------------------------
// bf16 GEMM: C[M x N] = A[M x K] @ Bt[N x K]^T + bias.
// ---------------------------------------------------------------------------
template <bool BF16_OUT>
__global__ __launch_bounds__(256, 2) void gemm_bt(
    const u16* __restrict__ A, const u16* __restrict__ Bt,
    const float* __restrict__ bias, void* __restrict__ Cv,
    int M, int N, int K)
{
  __shared__ u16 As[128 * 64];
  __shared__ u16 Bs[128 * 64];
  const int tid = threadIdx.x;
  const int lane = tid & 63;
  const int wv = tid >> 6;
  const int wm = wv >> 1, wn = wv & 1;
  const long row0 = (long)blockIdx.x * 128;
  const long col0 = (long)blockIdx.y * 128;
  const int lr8 = lane >> 3, lc8 = lane & 7;
  const int fr = lane & 15, fk = (lane >> 4) * 8;
  f32x4 acc[4][4] = {};

  for (int kt = 0; kt < K; kt += 64) {
    __syncthreads();
    #pragma unroll
    for (int ch = 0; ch < 4; ++ch) {
      const int r = wv * 32 + ch * 8;
      const u16* gA = A + (row0 + r + lr8) * (long)K + kt + lc8 * 8;
      __builtin_amdgcn_global_load_lds(
          (const __attribute__((address_space(1))) u32*)gA,
          (__attribute__((address_space(3))) u32*)&As[r * 64], 16, 0, 0);
      const u16* gB = Bt + (col0 + r + lr8) * (long)K + kt + lc8 * 8;
      __builtin_amdgcn_global_load_lds(
          (const __attribute__((address_space(1))) u32*)gB,
          (__attribute__((address_space(3))) u32*)&Bs[r * 64], 16, 0, 0);
    }
    __syncthreads();
    #pragma unroll
    for (int kk = 0; kk < 2; ++kk) {
      bf16x8 af[4], bfv[4];
      #pragma unroll
      for (int m = 0; m < 4; ++m)
        af[m] = *(const bf16x8*)&As[(wm * 64 + m * 16 + fr) * 64 + kk * 32 + fk];
      #pragma unroll
      for (int n = 0; n < 4; ++n)
        bfv[n] = *(const bf16x8*)&Bs[(wn * 64 + n * 16 + fr) * 64 + kk * 32 + fk];
      #pragma unroll
      for (int m = 0; m < 4; ++m)
        #pragma unroll
        for (int n = 0; n < 4; ++n)
          acc[m][n] = __builtin_amdgcn_mfma_f32_16x16x32_bf16(af[m], bfv[n], acc[m][n], 0, 0, 0);
    }
  }

  const int orow = (lane >> 4) * 4, ocol = lane & 15;
  #pragma unroll
  for (int m = 0; m < 4; ++m) {
    #pragma unroll
    for (int n = 0; n < 4; ++n) {
      const long cb = col0 + wn * 64 + n * 16 + ocol;
      const float bv = bias[cb];
      #pragma unroll
      for (int r = 0; r < 4; ++r) {
        const long rr = row0 + wm * 64 + m * 16 + orow + r;
        const float v = acc[m][n][r] + bv;
        if (BF16_OUT) ((u16*)Cv)[rr * (long)N + cb] = f2bf(v);
        else          ((float*)Cv)[rr * (long)N + cb] = v;
      }
    }
  }
}

// ---------------------------------------------------------------------------
// Persistent cooperative scan — r13 structure with two subtractive changes:
// (1) far/insurance slice DELETED. Transport = single sc1 near store
//     (write-through to L2+memory; eviction can only slow, never lose it)
//     + sc0 poll with sticky sc1 fallback. No agent atomics in the loop.
// (2) input prefetch issued right after the PHASE-1 poll (covered by the
//     ~1000cy MFMA+gates window => ~zero residual at the next poll).
// Everything else identical to r13 (wave-per-batch, frag-ordered LDS
// weights, 8+8 split MFMA chains, HS deferral).
// ---------------------------------------------------------------------------
#define SS 2048

__device__ __forceinline__ bool ge4(u32x4 v, u32 t) {
  return ((v[0] >> 16) >= t) & ((v[1] >> 16) >= t) &
         ((v[2] >> 16) >= t) & ((v[3] >> 16) >= t);
}

__device__ __forceinline__ void ld8_sc0(const u32* p, u32x4& a, u32x4& b) {
  asm volatile("global_load_dwordx4 %0, %2, off sc0\n\t"
               "global_load_dwordx4 %1, %3, off sc0\n\t"
               "s_waitcnt vmcnt(0)"
               : "=&v"(a), "=&v"(b) : "v"(p), "v"(p + 4));
}
__device__ __forceinline__ void ld8_sc1(const u32* p, u32x4& a, u32x4& b) {
  asm volatile("global_load_dwordx4 %0, %2, off sc1\n\t"
               "global_load_dwordx4 %1, %3, off sc1\n\t"
               "s_waitcnt vmcnt(0)"
               : "=&v"(a), "=&v"(b) : "v"(p), "v"(p + 4));
}

__device__ __forceinline__ void poll8(const u32* pn, u32 tag, int lvl, int* lvlsh,
                                      u32x4& a, u32x4& b) {
  if (lvl == 0) {
    int tries = 0;
    for (;;) {
      ld8_sc0(pn, a, b);
      if (ge4(a, tag) && ge4(b, tag)) return;
      if (++tries > 8000) { *lvlsh = 1; break; }   // sticky: sc1 reads same data
      if (tries > 256) __builtin_amdgcn_s_sleep(1);
    }
  }
  for (;;) {
    ld8_sc1(pn, a, b);
    if (ge4(a, tag) && ge4(b, tag)) return;
    __builtin_amdgcn_s_sleep(1);
  }
}

// producer: single sc1 store — write-through, visible at L2 scope & below
__device__ __forceinline__ void stnear(u32* pn, u32 word) {
  asm volatile("global_store_dword %0, %1, off sc1" :: "v"(pn), "v"(word) : "memory");
}

__global__ __launch_bounds__(256, 1) void scan_kernel(
    const u16* __restrict__ XZL, const float* __restrict__ XZO,
    const float* __restrict__ TS,
    const u16* __restrict__ WhlT, const u16* __restrict__ WhoT,
    u32* Ht, u32* HMt, u32* Ut,
    u16* __restrict__ HS,
    float* __restrict__ out_h, float* __restrict__ out_c,
    int* chk)
{
  const int tid = threadIdx.x;
  const int lane = tid & 63;
  const int wv = tid >> 6;
  const int fr = lane & 15;       // column index within the WG's 16 cols
  const int hi = lane >> 4;       // k-chunk / redundant-copy index

  __shared__ u16 whl_l[4][16][512];  // [gate][ks][lane*8] frag-ordered, 64 KB
  __shared__ u16 who_l[16][512];     // [ks][lane*8] frag-ordered, 16 KB
  __shared__ u16 stage_l[4][512];    // per-WAVE staging (h / hm / u), 4 KB
  __shared__ u16 xcl[256];
  __shared__ int lvl_sh;             // sticky escalation level (0/1)

  // ---- XCD discovery: publish own XCC_ID, gather all 256 ----
  if (tid == 0) {
    u32 xcc;
    asm volatile("s_getreg_b32 %0, hwreg(HW_REG_XCC_ID)" : "=s"(xcc));
    sta32((u32*)&chk[blockIdx.x], (xcc & 7u) + 1u);
    lvl_sh = 0;
  }
  {
    int v;
    do { v = loadai(&chk[tid]); } while (v == 0);
    xcl[tid] = (u16)(v - 1);
  }
  __syncthreads();

  // ---- group formation (identical computation in every WG) ----
  int g, w;
  {
    int cnt[8] = {0, 0, 0, 0, 0, 0, 0, 0};
    const int my = (int)xcl[blockIdx.x];
    int rank = 0;
    for (int bi = 0; bi < 256; ++bi) {
      const int e = (int)xcl[bi];
      ++cnt[e];
      rank += (e == my && bi < (int)blockIdx.x) ? 1 : 0;
    }
    bool ok = true;
    #pragma unroll
    for (int e = 0; e < 8; ++e) ok = ok && (cnt[e] == 32);
    if (ok) { g = my; w = rank; }
    else    { g = (int)(blockIdx.x & 7); w = (int)(blockIdx.x >> 3);
              if (tid == 0) lvl_sh = 1; }   // non-uniform placement: sc1 polls
  }
  const int j0 = w * 16;
  const int b = g * 4 + wv;          // this wave's batch

  // ---- stage weights into LDS, fragment order (one-time) ----
  {
    const int g4 = wv;               // wave wv stages gate wv
    #pragma unroll
    for (int ks = 0; ks < 16; ++ks)
      *(u16x8*)&whl_l[g4][ks][lane * 8] =
        *(const u16x8*)&WhlT[(size_t)(g4 * 512 + j0 + fr) * 512 + ks * 32 + (lane >> 4) * 8];
    for (int ks = wv; ks < 16; ks += 4)
      *(u16x8*)&who_l[ks][lane * 8] =
        *(const u16x8*)&WhoT[(size_t)(j0 + fr) * 512 + ks * 32 + (lane >> 4) * 8];
  }
  __syncthreads();                   // the ONLY barrier before the loop

  const int kc8 = hi * 8;
  u32* const Hb  = Ht  + g * 2048 + wv * 512;
  u32* const HMb = HMt + g * 2048 + wv * 512;
  u32* const Ub  = Ut  + g * 2048 + wv * 512;

  // ---- prologue input prefetch (s = 0), per lane col = j0+fr ----
  float zb_c[4], zo_c, t_c;
  {
    const u16* p = XZL + ((size_t)b * SS + 0) * 2048 + j0 + fr;
    zb_c[0] = b2f(p[0]); zb_c[1] = b2f(p[512]);
    zb_c[2] = b2f(p[1024]); zb_c[3] = b2f(p[1536]);
    zo_c = XZO[((size_t)b * SS + 0) * 512 + j0 + fr];
    t_c  = TS[(size_t)b * SS + 0];
  }

  float c_r = 0.0f;                  // LSTM cell state, register-resident
  u32x4 pa, pb;
  float hn_pend = 0.0f;              // deferred HS value

  for (int s = 0; s < SS; ++s) {
    const u32 tagv = (u32)(s + 1);
    int lvl = *(volatile int*)&lvl_sh;

    // ---- phase 1: poll h(own batch), stage to wave-private LDS ----
    if (s == 0) {
      u16x8 z8 = {0, 0, 0, 0, 0, 0, 0, 0};
      *(u16x8*)&stage_l[wv][lane * 8] = z8;
    } else {
      poll8(Hb + lane * 8, (u32)s, lvl, &lvl_sh, pa, pb);
      u16x8 hv;
      #pragma unroll
      for (int i = 0; i < 4; ++i) {
        hv[i] = (u16)(pa[i] & 0xffffu);
        hv[4 + i] = (u16)(pb[i] & 0xffffu);
      }
      *(u16x8*)&stage_l[wv][lane * 8] = hv;
      if (hi == 0)
        HS[((size_t)b * SS + (s - 1)) * 512 + j0 + fr] = f2bf(hn_pend);
    }
    // issue next-step input prefetch NOW — drains under phase-1 MFMA+gates
    const int sn = (s + 1 < SS) ? s + 1 : s;
    float zb_n[4], zo_n, t_n;
    {
      const u16* p = XZL + ((size_t)b * SS + sn) * 2048 + j0 + fr;
      zb_n[0] = b2f(p[0]); zb_n[1] = b2f(p[512]);
      zb_n[2] = b2f(p[1024]); zb_n[3] = b2f(p[1536]);
      zo_n = XZO[((size_t)b * SS + sn) * 512 + j0 + fr];
      t_n  = TS[(size_t)b * SS + sn];
    }

    // ---- z = h @ Whl : 4 gate chains, split 8+8 (broadcast-A) ----
    f32x4 az0a = {}, az0b = {}, az1a = {}, az1b = {};
    f32x4 az2a = {}, az2b = {}, az3a = {}, az3b = {};
    #pragma unroll
    for (int ks = 0; ks < 8; ++ks) {
      bf16x8 afa = *(const bf16x8*)&stage_l[wv][ks * 32 + kc8];
      bf16x8 afb = *(const bf16x8*)&stage_l[wv][(ks + 8) * 32 + kc8];
      az0a = __builtin_amdgcn_mfma_f32_16x16x32_bf16(afa, *(const bf16x8*)&whl_l[0][ks][lane * 8], az0a, 0, 0, 0);
      az0b = __builtin_amdgcn_mfma_f32_16x16x32_bf16(afb, *(const bf16x8*)&whl_l[0][ks + 8][lane * 8], az0b, 0, 0, 0);
      az1a = __builtin_amdgcn_mfma_f32_16x16x32_bf16(afa, *(const bf16x8*)&whl_l[1][ks][lane * 8], az1a, 0, 0, 0);
      az1b = __builtin_amdgcn_mfma_f32_16x16x32_bf16(afb, *(const bf16x8*)&whl_l[1][ks + 8][lane * 8], az1b, 0, 0, 0);
      az2a = __builtin_amdgcn_mfma_f32_16x16x32_bf16(afa, *(const bf16x8*)&whl_l[2][ks][lane * 8], az2a, 0, 0, 0);
      az2b = __builtin_amdgcn_mfma_f32_16x16x32_bf16(afb, *(const bf16x8*)&whl_l[2][ks + 8][lane * 8], az2b, 0, 0, 0);
      az3a = __builtin_amdgcn_mfma_f32_16x16x32_bf16(afa, *(const bf16x8*)&whl_l[3][ks][lane * 8], az3a, 0, 0, 0);
      az3b = __builtin_amdgcn_mfma_f32_16x16x32_bf16(afb, *(const bf16x8*)&whl_l[3][ks + 8][lane * 8], az3b, 0, 0, 0);
    }

    // ---- gates (all 64 lanes; 4 redundant copies across hi) ----
    const float zi = az0a[0] + az0b[0] + zb_c[0];
    const float zf = az1a[0] + az1b[0] + zb_c[1];
    const float zg = az2a[0] + az2b[0] + zb_c[2];
    const float zo = az3a[0] + az3b[0] + zb_c[3];
    const float cn = sigf(zf) * c_r + sigf(zi) * tanh_(zg);
    const float hm = sigf(zo) * tanh_(cn);
    c_r = cn;
    if (hi == 0)
      stnear(&HMb[j0 + fr], (tagv << 16) | (u32)f2bf(hm));

    // ---- phase 2: poll hm ----
    lvl = *(volatile int*)&lvl_sh;
    poll8(HMb + lane * 8, tagv, lvl, &lvl_sh, pa, pb);
    {
      u16x8 hv;
      #pragma unroll
      for (int i = 0; i < 4; ++i) {
        hv[i] = (u16)(pa[i] & 0xffffu);
        hv[4 + i] = (u16)(pb[i] & 0xffffu);
      }
      *(u16x8*)&stage_l[wv][lane * 8] = hv;
    }
    f32x4 aka = {}, akb = {};
    #pragma unroll
    for (int ks = 0; ks < 8; ++ks) {
      bf16x8 afa = *(const bf16x8*)&stage_l[wv][ks * 32 + kc8];
      bf16x8 afb = *(const bf16x8*)&stage_l[wv][(ks + 8) * 32 + kc8];
      aka = __builtin_amdgcn_mfma_f32_16x16x32_bf16(afa, *(const bf16x8*)&who_l[ks][lane * 8], aka, 0, 0, 0);
      akb = __builtin_amdgcn_mfma_f32_16x16x32_bf16(afb, *(const bf16x8*)&who_l[ks + 8][lane * 8], akb, 0, 0, 0);
    }
    const float k1 = tanh_(zo_c + aka[0] + akb[0]);
    const float uu = hm + t_c * k1;
    if (hi == 0)
      stnear(&Ub[j0 + fr], (tagv << 16) | (u32)f2bf(uu));

    // ---- phase 3: poll u ----
    lvl = *(volatile int*)&lvl_sh;
    poll8(Ub + lane * 8, tagv, lvl, &lvl_sh, pa, pb);
    {
      u16x8 hv;
      #pragma unroll
      for (int i = 0; i < 4; ++i) {
        hv[i] = (u16)(pa[i] & 0xffffu);
        hv[4 + i] = (u16)(pb[i] & 0xffffu);
      }
      *(u16x8*)&stage_l[wv][lane * 8] = hv;
    }
    f32x4 a2a = {}, a2b = {};
    #pragma unroll
    for (int ks = 0; ks < 8; ++ks) {
      bf16x8 afa = *(const bf16x8*)&stage_l[wv][ks * 32 + kc8];
      bf16x8 afb = *(const bf16x8*)&stage_l[wv][(ks + 8) * 32 + kc8];
      a2a = __builtin_amdgcn_mfma_f32_16x16x32_bf16(afa, *(const bf16x8*)&who_l[ks][lane * 8], a2a, 0, 0, 0);
      a2b = __builtin_amdgcn_mfma_f32_16x16x32_bf16(afb, *(const bf16x8*)&who_l[ks + 8][lane * 8], a2b, 0, 0, 0);
    }
    const float k2 = tanh_(zo_c + a2a[0] + a2b[0]);
    const float hn = hm + 0.5f * t_c * (k1 + k2);
    if (hi == 0) {
      stnear(&Hb[j0 + fr], (tagv << 16) | (u32)f2bf(hn));
      hn_pend = hn;                  // HS store deferred to next phase-1
    }

    #pragma unroll
    for (int i = 0; i < 4; ++i) zb_c[i] = zb_n[i];
    zo_c = zo_n; t_c = t_n;
  }

  if (hi == 0) {
    HS[((size_t)b * SS + (SS - 1)) * 512 + j0 + fr] = f2bf(hn_pend);
    out_h[(size_t)b * 512 + j0 + fr] = hn_pend;
    out_c[(size_t)b * 512 + j0 + fr] = c_r;
  }
}

// ---------------------------------------------------------------------------
// Host launch
// ---------------------------------------------------------------------------
extern "C" void kernel_launch(void* const* d_in, const int* in_sizes, int n_in,
                              void* d_out, int out_size, void* d_ws, size_t ws_size,
                              hipStream_t stream)
{
  const long B = 32, S = 2048, O = 512;
  const long MS = B * S; // 65536 rows

  const float* x   = (const float*)d_in[0];
  const float* ts  = (const float*)d_in[1];
  const float* Wxl = (const float*)d_in[2];
  const float* Whl = (const float*)d_in[3];
  const float* bl  = (const float*)d_in[4];
  const float* Wxo = (const float*)d_in[5];
  const float* Who = (const float*)d_in[6];
  const float* bo  = (const float*)d_in[7];
  const float* Wfc = (const float*)d_in[8];
  const float* bfc = (const float*)d_in[9];

  float* out = (float*)d_out;
  float* out_h = out + MS * O;
  float* out_c = out_h + B * 512;

  char* ws = (char*)d_ws;
  size_t off = 0;
  auto alloc = [&](size_t bytes) -> void* {
    void* p = ws + off;
    off += (bytes + 255) & ~(size_t)255;
    return p;
  };
  u16*   XZL  = (u16*)  alloc(MS * 2048 * 2);     // 268 MB, bf16
  u16*   xb   = (u16*)  alloc(MS * 512 * 2);      // 67 MB; HS aliases this
  u16*   HS   = xb;
  u16*   WxlT = (u16*)  alloc(2048 * 512 * 2);
  u16*   WhlT = (u16*)  alloc(2048 * 512 * 2);
  u16*   WxoT = (u16*)  alloc(512 * 512 * 2);
  u16*   WhoT = (u16*)  alloc(512 * 512 * 2);
  u16*   WfcT = (u16*)  alloc(512 * 512 * 2);
  u32*   Ht   = (u32*)  alloc(8 * 2048 * 4);
  u32*   HMt  = (u32*)  alloc(8 * 2048 * 4);
  u32*   Ut   = (u32*)  alloc(8 * 2048 * 4);
  int*   chk  = (int*)  alloc(1024);

  float* XZO = out;   // (B,S,H) fp32 scratch in d_out; overwritten by final GEMM

  if (off > ws_size) return;

  // Reset tag/check buffers every launch (graph-replay stale tags).
  hipMemsetAsync(Ht, 0, 8 * 2048 * 4, stream);
  hipMemsetAsync(HMt, 0, 8 * 2048 * 4, stream);
  hipMemsetAsync(Ut, 0, 8 * 2048 * 4, stream);
  hipMemsetAsync(chk, 0, 1024, stream);

  cvt_bf16_vec<<<2048, 256, 0, stream>>>(x, xb, (int)(MS * 512 / 4));
  transpose_f32_bf16<<<dim3(64, 16), 256, 0, stream>>>(Wxl, WxlT, 512, 2048);
  transpose_f32_bf16<<<dim3(64, 16), 256, 0, stream>>>(Whl, WhlT, 512, 2048);
  transpose_f32_bf16<<<dim3(16, 16), 256, 0, stream>>>(Wxo, WxoT, 512, 512);
  transpose_f32_bf16<<<dim3(16, 16), 256, 0, stream>>>(Who, WhoT, 512, 512);
  transpose_f32_bf16<<<dim3(16, 16), 256, 0, stream>>>(Wfc, WfcT, 512, 512);

  gemm_bt<true ><<<dim3(512, 16), 256, 0, stream>>>(xb, WxlT, bl, XZL, (int)MS, 2048, 512);
  gemm_bt<false><<<dim3(512, 4), 256, 0, stream>>>(xb, WxoT, bo, XZO, (int)MS, 512, 512);

  {
    void* args[] = { (void*)&XZL, (void*)&XZO, (void*)&ts, (void*)&WhlT, (void*)&WhoT,
                     (void*)&Ht, (void*)&HMt, (void*)&Ut, (void*)&HS,
                     (void*)&out_h, (void*)&out_c, (void*)&chk };
    hipLaunchCooperativeKernel((void*)scan_kernel, dim3(256), dim3(256), args, 0, stream);
  }

  gemm_bt<false><<<dim3(512, 4), 256, 0, stream>>>(HS, WfcT, bfc, out, (int)MS, 512, 512);
}